// Round 1
// 725.784 us; speedup vs baseline: 1.1776x; 1.1776x over previous
//
#include <hip/hip_runtime.h>

#define NB 8
#define NC 512
#define NL 8192
#define NH 8
#define ND 64

typedef float f32x4 __attribute__((ext_vector_type(4)));
typedef __bf16 bf16x8 __attribute__((ext_vector_type(8)));
typedef unsigned int u32x4 __attribute__((ext_vector_type(4)));

__device__ __forceinline__ unsigned short f2bf(float f) {
    unsigned u = __builtin_bit_cast(unsigned, f);
    u += 0x7fffu + ((u >> 16) & 1u);
    return (unsigned short)(u >> 16);
}
__device__ __forceinline__ float bf2f(unsigned short s) {
    unsigned u = ((unsigned)s) << 16;
    return __builtin_bit_cast(float, u);
}
__device__ __forceinline__ float bf2f_lo(unsigned w) {
    return __builtin_bit_cast(float, w << 16);
}
__device__ __forceinline__ float bf2f_hi(unsigned w) {
    return __builtin_bit_cast(float, w & 0xffff0000u);
}
__device__ __forceinline__ bf16x8 frag_from_u32x4(u32x4 v) {
    return __builtin_bit_cast(bf16x8, v);
}
// LDS fragment load with only-4B-aligned rows -> dword reads
__device__ __forceinline__ bf16x8 ld_frag_lds(const unsigned short* p) {
    const unsigned* q = (const unsigned*)p;
    u32x4 v = { q[0], q[1], q[2], q[3] };
    return frag_from_u32x4(v);
}
// Global fragment load: 16B aligned
__device__ __forceinline__ bf16x8 ld_frag_g16(const unsigned short* p) {
    return frag_from_u32x4(*(const u32x4*)p);
}

__global__ __launch_bounds__(256) void cvt_w_kernel(const float* __restrict__ s,
                                                    unsigned short* __restrict__ d, int n) {
    int i = blockIdx.x * 256 + threadIdx.x;
    if (i < n) d[i] = f2bf(s[i]);
}

__global__ __launch_bounds__(256) void zero_kernel(float* __restrict__ p, int n) {
    int i = blockIdx.x * 256 + threadIdx.x;
    if (i < n) p[i] = 0.f;
}

// bkv = [bk ; bv]
__global__ __launch_bounds__(256) void concat_bias_kernel(const float* __restrict__ a,
                                                          const float* __restrict__ b,
                                                          float* __restrict__ d) {
    int i = blockIdx.x * 256 + threadIdx.x;
    d[i] = (i < NC) ? a[i] : b[i - NC];
}

// Y[b,o,l] = sum_c W[o,c] X[b,c,l] + bias[o]  (+ resid)  (+ fused per-head q-softmax)
// MT = number of 128-row m-tiles (OC = MT*128). grid: (64*MT, NB), block 256.
// XCD-aware swizzle: all MT blocks sharing one X panel (same nt) land on the same XCD
// (round-robin wg->XCD assignment: same bx%8 => same XCD => shared 4MB L2).
template<int MT, bool XBF, bool RESID, bool PERB, bool QSM>
__global__ __launch_bounds__(256) void gemm_kernel(
    const unsigned short* __restrict__ Wb,   // [OC,512] bf16 (PERB: per-batch [B][512][512])
    const void* __restrict__ Xv,             // [B,512,L] float or bf16(ushort)
    const float* __restrict__ bias,          // [OC]
    const float* __restrict__ resid,         // [B,512,L] float (RESID only)
    void* __restrict__ Yv)                   // bf16 (ushort) or float
{
    const int bx = blockIdx.x;
    const int g  = bx >> 3;
    const int mt = g % MT;
    const int nt = (g / MT) * 8 + (bx & 7);  // 0..63; same nt => same XCD
    const int b  = blockIdx.y;
    const int t  = threadIdx.x;
    const int wave = t >> 6, lane = t & 63;
    const int m0 = mt * 128, n0 = nt * 128;
    const int wm = (wave & 1) * 64, wn = (wave >> 1) * 64;
    const int OC = MT * 128;

    __shared__ alignas(16) unsigned short lA[128][34]; // [m][k], stride 34 (17 dwords, odd)
    __shared__ alignas(16) unsigned short lX[128][34]; // [n=l][k=c] transposed

    f32x4 acc[4][4] = {};

    const float* Xf = (const float*)Xv;
    const unsigned short* Xh = (const unsigned short*)Xv;
    const size_t xbase = (size_t)b * NC * NL;
    const unsigned short* Wp = Wb + (PERB ? (size_t)b * NC * NC : 0);

    for (int k0 = 0; k0 < NC; k0 += 32) {
        // stage W (bf16), 128x32
        {
            int id = t;
            #pragma unroll
            for (int it = 0; it < 2; ++it, id += 256) {
                const int r = id >> 2, s = id & 3;
                u32x4 v = *(const u32x4*)(Wp + (size_t)(m0 + r) * NC + k0 + s * 8);
                unsigned* p = (unsigned*)&lA[r][s * 8];
                p[0] = v.x; p[1] = v.y; p[2] = v.z; p[3] = v.w;
            }
        }
        // stage X transposed into [l][c]
        if constexpr (!XBF) {
            #pragma unroll
            for (int it = 0; it < 16; ++it) {
                const int kr = it * 2 + (t >> 7);
                const int l  = t & 127;
                lX[l][kr] = f2bf(Xf[xbase + (size_t)(k0 + kr) * NL + n0 + l]);
            }
        } else {
            #pragma unroll
            for (int it = 0; it < 8; ++it) {
                const int kr = it * 4 + (t >> 6);
                const int l2 = (t & 63) * 2;
                unsigned v = *(const unsigned*)(Xh + xbase + (size_t)(k0 + kr) * NL + n0 + l2);
                lX[l2][kr]     = (unsigned short)(v & 0xffffu);
                lX[l2 + 1][kr] = (unsigned short)(v >> 16);
            }
        }
        __syncthreads();

        const int koff = (lane >> 4) * 8;
        bf16x8 af[4], bfx[4];
        #pragma unroll
        for (int i = 0; i < 4; ++i)
            af[i] = ld_frag_lds(&lA[wm + i * 16 + (lane & 15)][koff]);
        #pragma unroll
        for (int j = 0; j < 4; ++j)
            bfx[j] = ld_frag_lds(&lX[wn + j * 16 + (lane & 15)][koff]);
        #pragma unroll
        for (int i = 0; i < 4; ++i)
            #pragma unroll
            for (int j = 0; j < 4; ++j)
                acc[i][j] = __builtin_amdgcn_mfma_f32_16x16x32_bf16(af[i], bfx[j], acc[i][j], 0, 0, 0);
        __syncthreads();
    }

    // epilogue: C/D layout col=lane&15, row=(lane>>4)*4+reg
    const int col = lane & 15, row0 = (lane >> 4) * 4;

    if constexpr (QSM) {
        // fused per-head softmax over the 64 output channels (= this wave's 64 rows).
        // Column j*16+col is held by lanes {col, col^16, col^32, col^48}: 16 acc values
        // per lane + shfl_xor(16/32) reduce = full 64-row softmax.
        #pragma unroll
        for (int i = 0; i < 4; ++i)
            #pragma unroll
            for (int r = 0; r < 4; ++r) {
                const float bo = bias[m0 + wm + i * 16 + row0 + r];
                #pragma unroll
                for (int j = 0; j < 4; ++j) acc[i][j][r] += bo;
            }
        float inv[4];
        #pragma unroll
        for (int j = 0; j < 4; ++j) {
            float m = -1e30f;
            #pragma unroll
            for (int i = 0; i < 4; ++i)
                #pragma unroll
                for (int r = 0; r < 4; ++r) m = fmaxf(m, acc[i][j][r]);
            m = fmaxf(m, __shfl_xor(m, 16));
            m = fmaxf(m, __shfl_xor(m, 32));
            float s = 0.f;
            #pragma unroll
            for (int i = 0; i < 4; ++i)
                #pragma unroll
                for (int r = 0; r < 4; ++r) {
                    const float e = __expf(acc[i][j][r] - m);
                    acc[i][j][r] = e;
                    s += e;
                }
            s += __shfl_xor(s, 16);
            s += __shfl_xor(s, 32);
            inv[j] = 1.0f / s;
        }
        unsigned short* Y = (unsigned short*)Yv;
        #pragma unroll
        for (int i = 0; i < 4; ++i)
            #pragma unroll
            for (int r = 0; r < 4; ++r) {
                const int o = m0 + wm + i * 16 + row0 + r;
                const size_t rb = (size_t)b * OC * NL + (size_t)o * NL + n0 + wn;
                #pragma unroll
                for (int j = 0; j < 4; ++j)
                    Y[rb + j * 16 + col] = f2bf(acc[i][j][r] * inv[j]);
            }
    } else {
        #pragma unroll
        for (int i = 0; i < 4; ++i) {
            #pragma unroll
            for (int r = 0; r < 4; ++r) {
                const int o = m0 + wm + i * 16 + row0 + r;
                const float bo = bias[o];
                const size_t rb = (size_t)b * OC * NL + (size_t)o * NL + n0 + wn;
                if constexpr (RESID) {
                    float* Y = (float*)Yv;
                    #pragma unroll
                    for (int j = 0; j < 4; ++j) {
                        const size_t idx = rb + j * 16 + col;
                        Y[idx] = acc[i][j][r] + bo + resid[idx];
                    }
                } else {
                    unsigned short* Y = (unsigned short*)Yv;
                    #pragma unroll
                    for (int j = 0; j < 4; ++j)
                        Y[rb + j * 16 + col] = f2bf(acc[i][j][r] + bo);
                }
            }
        }
    }
}

// in-place softmax over rows of 8192 (bf16), one block per row (K channels of KVp)
__global__ __launch_bounds__(256) void softmax_rows(unsigned short* __restrict__ KV) {
    const int row = blockIdx.x;             // 0..NB*NC-1
    const int t = threadIdx.x;
    const int wave = t >> 6, lane = t & 63;
    unsigned short* p = KV + ((size_t)(row >> 9) * 2 * NC + (row & 511)) * NL;

    float v[32];
    float mx = -1e30f;
    #pragma unroll
    for (int i = 0; i < 4; ++i) {
        u32x4 raw = *(const u32x4*)(p + (size_t)(i * 256 + t) * 8);
        #pragma unroll
        for (int d = 0; d < 4; ++d) {
            unsigned w = raw[d];
            v[i * 8 + d * 2]     = bf2f_lo(w);
            v[i * 8 + d * 2 + 1] = bf2f_hi(w);
        }
        #pragma unroll
        for (int j = 0; j < 8; ++j) mx = fmaxf(mx, v[i * 8 + j]);
    }
    #pragma unroll
    for (int off = 32; off > 0; off >>= 1) mx = fmaxf(mx, __shfl_down(mx, off));
    __shared__ float red[16];
    if (lane == 0) red[wave] = mx;
    __syncthreads();
    mx = fmaxf(fmaxf(red[0], red[1]), fmaxf(red[2], red[3]));

    float s = 0.f;
    #pragma unroll
    for (int i = 0; i < 32; ++i) { v[i] = __expf(v[i] - mx); s += v[i]; }
    #pragma unroll
    for (int off = 32; off > 0; off >>= 1) s += __shfl_down(s, off);
    if (lane == 0) red[8 + wave] = s;
    __syncthreads();
    s = red[8] + red[9] + red[10] + red[11];
    const float inv = 1.0f / s;

    #pragma unroll
    for (int i = 0; i < 4; ++i) {
        u32x4 outw;
        #pragma unroll
        for (int d = 0; d < 4; ++d) {
            unsigned lo = f2bf(v[i * 8 + d * 2] * inv);
            unsigned hi = f2bf(v[i * 8 + d * 2 + 1] * inv);
            outw[d] = lo | (hi << 16);
        }
        *(u32x4*)(p + (size_t)(i * 256 + t) * 8) = outw;
    }
}

// ctx[bh,k,v] = sum_l Ksm[b,h,k,l] * V[b,h,v,l]   grid (64, 16 L-splits), atomicAdd
__global__ __launch_bounds__(256) void ctx_kernel(
    const unsigned short* __restrict__ KV,   // [B][1024][L]: rows 0-511 K(softmaxed), 512-1023 V
    float* __restrict__ ctx)                 // [64][64][64]
{
    const int bh = blockIdx.x;
    const int sp = blockIdx.y;
    const int t = threadIdx.x;
    const int wave = t >> 6, lane = t & 63;
    const int b = bh >> 3, h = bh & 7;
    const size_t base_k = ((size_t)b * 2 * NC + h * ND) * NL;
    const size_t base_v = base_k + (size_t)NC * NL;
    const int i = wave * 16 + (lane & 15);
    const int koff = (lane >> 4) * 8;
    const unsigned short* Ka = KV + base_k + (size_t)i * NL + koff;

    f32x4 acc[4] = {};
    const int l0 = sp * (NL / 16);
    for (int l = l0; l < l0 + (NL / 16); l += 32) {
        bf16x8 a = ld_frag_g16(Ka + l);
        #pragma unroll
        for (int j = 0; j < 4; ++j) {
            bf16x8 bv = ld_frag_g16(KV + base_v + (size_t)(j * 16 + (lane & 15)) * NL + l + koff);
            acc[j] = __builtin_amdgcn_mfma_f32_16x16x32_bf16(a, bv, acc[j], 0, 0, 0);
        }
    }
    const int col = lane & 15, row0 = (lane >> 4) * 4;
    #pragma unroll
    for (int j = 0; j < 4; ++j)
        #pragma unroll
        for (int r = 0; r < 4; ++r)
            atomicAdd(&ctx[(size_t)bh * (ND * ND) + (size_t)(wave * 16 + row0 + r) * ND + j * 16 + col],
                      acc[j][r]);
}

// M_b[o, h*64+k] = sum_v Wr[o, h*64+v] * ctx[b,h,k,v]
// grid 64 blocks (bh), 512 threads = 8 waves; wave covers 64 o-rows
__global__ __launch_bounds__(512) void fold_kernel(
    const unsigned short* __restrict__ Wrb,  // [512][512] bf16
    const float* __restrict__ ctxb,          // [64][64][64]
    unsigned short* __restrict__ Mb)         // [B][512][512] bf16
{
    const int bh = blockIdx.x;
    const int b = bh >> 3, h = bh & 7;
    const int t = threadIdx.x;
    const int wave = t >> 6, lane = t & 63;

    __shared__ unsigned short lc[64 * 66];   // ctx bf16 [k][v], padded stride 66
    const float* cs = ctxb + (size_t)bh * (ND * ND);
    #pragma unroll
    for (int it = 0; it < 8; ++it) {
        int i = it * 512 + t;
        lc[(i >> 6) * 66 + (i & 63)] = f2bf(cs[i]);
    }
    __syncthreads();

    const int koff = (lane >> 4) * 8;
    f32x4 acc[4][4] = {};
    #pragma unroll
    for (int kk = 0; kk < 64; kk += 32) {
        bf16x8 af[4], bfx[4];
        #pragma unroll
        for (int i = 0; i < 4; ++i)
            af[i] = ld_frag_g16(Wrb + (size_t)(wave * 64 + i * 16 + (lane & 15)) * NC
                                + h * ND + kk + koff);
        #pragma unroll
        for (int j = 0; j < 4; ++j)
            bfx[j] = ld_frag_lds(&lc[(j * 16 + (lane & 15)) * 66 + kk + koff]);
        #pragma unroll
        for (int i = 0; i < 4; ++i)
            #pragma unroll
            for (int j = 0; j < 4; ++j)
                acc[i][j] = __builtin_amdgcn_mfma_f32_16x16x32_bf16(af[i], bfx[j], acc[i][j], 0, 0, 0);
    }

    const int col = lane & 15, row0 = (lane >> 4) * 4;
    #pragma unroll
    for (int i = 0; i < 4; ++i)
        #pragma unroll
        for (int r = 0; r < 4; ++r) {
            const int o = wave * 64 + i * 16 + row0 + r;
            #pragma unroll
            for (int j = 0; j < 4; ++j)
                Mb[(size_t)b * NC * NC + (size_t)o * NC + h * ND + j * 16 + col]
                    = f2bf(acc[i][j][r]);
        }
}

extern "C" void kernel_launch(void* const* d_in, const int* in_sizes, int n_in,
                              void* d_out, int out_size, void* d_ws, size_t ws_size,
                              hipStream_t stream) {
    (void)in_sizes; (void)n_in; (void)out_size; (void)ws_size;
    const float* input_   = (const float*)d_in[0];
    const float* context_ = (const float*)d_in[1];
    const float* Wk = (const float*)d_in[2];
    const float* bk = (const float*)d_in[3];
    const float* Wq = (const float*)d_in[4];
    const float* bq = (const float*)d_in[5];
    const float* Wv = (const float*)d_in[6];
    const float* bv = (const float*)d_in[7];
    const float* Wr = (const float*)d_in[8];
    const float* br = (const float*)d_in[9];
    float* out = (float*)d_out;

    // workspace layout (~204 MB):
    char* ws = (char*)d_ws;
    unsigned short* Wkvb = (unsigned short*)ws;                     // [1024][512] bf16 = 1 MB
    unsigned short* Wqb  = Wkvb + 2 * NC * NC;                      // 512 KB
    unsigned short* Wrb  = Wqb + NC * NC;                           // 512 KB
    float* bkv  = (float*)(Wrb + NC * NC);                          // 4 KB
    float* ctxb = bkv + 2 * NC;                                     // 1 MB
    unsigned short* KVp = (unsigned short*)(ctxb + NB * NH * ND * ND); // [B][1024][L] = 134 MB
    unsigned short* Qp  = KVp + (size_t)NB * 2 * NC * NL;           // 67 MB
    unsigned short* Mb  = KVp;                                      // reuse KVp after ctx/fold

    const int wN = NC * NC;
    cvt_w_kernel<<<wN / 256, 256, 0, stream>>>(Wk, Wkvb, wN);
    cvt_w_kernel<<<wN / 256, 256, 0, stream>>>(Wv, Wkvb + wN, wN);
    cvt_w_kernel<<<wN / 256, 256, 0, stream>>>(Wq, Wqb, wN);
    cvt_w_kernel<<<wN / 256, 256, 0, stream>>>(Wr, Wrb, wN);
    concat_bias_kernel<<<4, 256, 0, stream>>>(bk, bv, bkv);
    zero_kernel<<<(NB * NH * ND * ND) / 256, 256, 0, stream>>>(ctxb, NB * NH * ND * ND);

    // K+V fused projection: [Wk;Wv] (1024x512) @ context -> KVp
    gemm_kernel<8, false, false, false, false><<<dim3(64 * 8, NB), 256, 0, stream>>>(
        Wkvb, context_, bkv, nullptr, KVp);
    // Q projection with fused per-head softmax over the 64 key channels
    gemm_kernel<4, false, false, false, true><<<dim3(64 * 4, NB), 256, 0, stream>>>(
        Wqb, input_, bq, nullptr, Qp);

    softmax_rows<<<NB * NC, 256, 0, stream>>>(KVp);
    ctx_kernel<<<dim3(NB * NH, 16), 256, 0, stream>>>(KVp, ctxb);
    fold_kernel<<<NB * NH, 512, 0, stream>>>(Wrb, ctxb, Mb);

    // out = M_b @ qsoftmax(Qp) + br + input
    gemm_kernel<4, true, true, true, false><<<dim3(64 * 4, NB), 256, 0, stream>>>(
        Mb, Qp, br, input_, out);
}

// Round 2
// 654.620 us; speedup vs baseline: 1.3056x; 1.1087x over previous
//
#include <hip/hip_runtime.h>

#define NB 8
#define NC 512
#define NL 8192
#define NH 8
#define ND 64

typedef float f32x4 __attribute__((ext_vector_type(4)));
typedef __bf16 bf16x8 __attribute__((ext_vector_type(8)));
typedef unsigned int u32x4 __attribute__((ext_vector_type(4)));

__device__ __forceinline__ unsigned short f2bf(float f) {
    unsigned u = __builtin_bit_cast(unsigned, f);
    u += 0x7fffu + ((u >> 16) & 1u);
    return (unsigned short)(u >> 16);
}
__device__ __forceinline__ float bf2f_lo(unsigned w) {
    return __builtin_bit_cast(float, w << 16);
}
__device__ __forceinline__ float bf2f_hi(unsigned w) {
    return __builtin_bit_cast(float, w & 0xffff0000u);
}
__device__ __forceinline__ bf16x8 frag_from_u32x4(u32x4 v) {
    return __builtin_bit_cast(bf16x8, v);
}
// LDS fragment load with only-4B-aligned rows -> dword reads (fold kernel only)
__device__ __forceinline__ bf16x8 ld_frag_lds(const unsigned short* p) {
    const unsigned* q = (const unsigned*)p;
    u32x4 v = { q[0], q[1], q[2], q[3] };
    return frag_from_u32x4(v);
}
// Global fragment load: 16B aligned
__device__ __forceinline__ bf16x8 ld_frag_g16(const unsigned short* p) {
    return frag_from_u32x4(*(const u32x4*)p);
}

// async global->LDS, 16B per lane. dest = wave-uniform base + lane*16 (m104).
__device__ __forceinline__ void gload16(const unsigned short* g, unsigned short* l) {
    __builtin_amdgcn_global_load_lds(
        (const __attribute__((address_space(1))) unsigned int*)g,
        (__attribute__((address_space(3))) unsigned int*)l, 16, 0, 0);
}

__global__ __launch_bounds__(256) void cvt_w_kernel(const float* __restrict__ s,
                                                    unsigned short* __restrict__ d, int n) {
    int i = blockIdx.x * 256 + threadIdx.x;
    if (i < n) d[i] = f2bf(s[i]);
}

__global__ __launch_bounds__(256) void zero_kernel(float* __restrict__ p, int n) {
    int i = blockIdx.x * 256 + threadIdx.x;
    if (i < n) p[i] = 0.f;
}

// bkv = [bk ; bv]
__global__ __launch_bounds__(256) void concat_bias_kernel(const float* __restrict__ a,
                                                          const float* __restrict__ b,
                                                          float* __restrict__ d) {
    int i = blockIdx.x * 256 + threadIdx.x;
    d[i] = (i < NC) ? a[i] : b[i - NC];
}

// fp32 [b][c][l] -> bf16 [b][l][c]. 64x64 tiles through LDS.
// LDS layout XOR-swizzled on 8B granules: elem(c,l) at c*64 + ((l>>2)^((c>>2)&15))*4 + (l&3)
// phase2 reads verified 2-way (free); phase2 global writes 128B-contiguous per 8 lanes.
__device__ __forceinline__ int ltidx(int c, int l) {
    return c * 64 + ((((l) >> 2) ^ ((c >> 2) & 15)) << 2) + (l & 3);
}
__global__ __launch_bounds__(256) void transpose_cvt_kernel(
    const float* __restrict__ X, unsigned short* __restrict__ Y)
{
    const int b = blockIdx.z;
    const int l0 = blockIdx.x * 64, c0 = blockIdx.y * 64;
    const int t = threadIdx.x;
    __shared__ alignas(16) unsigned short lt[64 * 64];
    const float* Xb = X + (size_t)b * NC * NL;
    #pragma unroll
    for (int it = 0; it < 4; ++it) {
        const int c = it * 16 + (t >> 4), l4 = (t & 15) * 4;
        f32x4 v = *(const f32x4*)(Xb + (size_t)(c0 + c) * NL + l0 + l4);
        unsigned lo = f2bf(v.x) | ((unsigned)f2bf(v.y) << 16);
        unsigned hi = f2bf(v.z) | ((unsigned)f2bf(v.w) << 16);
        unsigned* p = (unsigned*)&lt[ltidx(c, l4)];
        p[0] = lo; p[1] = hi;
    }
    __syncthreads();
    unsigned short* Yb = Y + (size_t)b * NL * NC;
    #pragma unroll
    for (int it = 0; it < 2; ++it) {
        const int l = it * 32 + (t >> 3), c8 = (t & 7) * 8;
        u32x4 o;
        #pragma unroll
        for (int d = 0; d < 4; ++d) {
            unsigned lo = lt[ltidx(c8 + 2 * d, l)];
            unsigned hi = lt[ltidx(c8 + 2 * d + 1, l)];
            o[d] = lo | (hi << 16);
        }
        *(u32x4*)(Yb + (size_t)(l0 + l) * NC + c0 + c8) = o;
    }
}

// Y[b,o,l] = sum_c W[o,c] Xt[b,l,c] + bias[o]  (+ resid / + fused transposed q-softmax out)
// Both operands bf16 row-major [row][512]. m97 structure: global_load_lds(16B) staging into
// linear LDS, XOR chunk swizzle phys = r*4 + (q ^ ((r>>1)&3)) (global src pre-swizzled,
// reads 2-way conflict-free), ds_read_b128 fragments, 16 MFMA / wave / K-step.
// grid: (64*MT, NB), block 256, XCD-aware swizzle (same nt => same XCD).
template<int MT, bool RESID, bool PERB, bool QSMT>
__global__ __launch_bounds__(256) void gemm_kernel(
    const unsigned short* __restrict__ Wb,   // [OC][512] bf16 (PERB: [B][512][512])
    const unsigned short* __restrict__ Xt,   // [B][L][512] bf16
    const float* __restrict__ bias,          // [OC]
    const float* __restrict__ resid,         // [B,512,L] float (RESID only)
    void* __restrict__ Yv)                   // bf16 or float
{
    const int bx = blockIdx.x;
    const int g  = bx >> 3;
    const int mt = g % MT;
    const int nt = (g / MT) * 8 + (bx & 7);
    const int b  = blockIdx.y;
    const int t  = threadIdx.x;
    const int wave = t >> 6, lane = t & 63;
    const int m0 = mt * 128, n0 = nt * 128;
    const int wm = (wave & 1) * 64, wn = (wave >> 1) * 64;
    const int OC = MT * 128;

    __shared__ alignas(16) unsigned short lA[128 * 32];
    __shared__ alignas(16) unsigned short lX[128 * 32];

    f32x4 acc[4][4] = {};

    const unsigned short* Wp = Wb + (PERB ? (size_t)b * NC * NC : 0);
    const unsigned short* Xb = Xt + (size_t)b * NL * NC;

    const int lr = lane & 15, q = lane >> 4;
    // fragment byte offsets; swizzle term constant across the 16-row unroll (16*4 % 8 == 0)
    const unsigned aoff = (unsigned)((wm + lr) * 64 + (q ^ (((wm + lr) >> 1) & 3)) * 16);
    const unsigned boff = (unsigned)((wn + lr) * 64 + (q ^ (((wn + lr) >> 1) & 3)) * 16);
    const int pb0 = wave * 128;   // this wave's chunk range [pb0, pb0+128)

    for (int k0 = 0; k0 < NC; k0 += 32) {
        #pragma unroll
        for (int cc = 0; cc < 2; ++cc) {
            const int pb = pb0 + cc * 64;      // wave-uniform LDS base chunk
            const int p  = pb + lane;          // this lane's chunk
            const int r  = p >> 2;
            const int qq = (p & 3) ^ ((r >> 1) & 3);
            gload16(Wp + (size_t)(m0 + r) * NC + k0 + qq * 8, &lA[pb * 8]);
            gload16(Xb + (size_t)(n0 + r) * NC + k0 + qq * 8, &lX[pb * 8]);
        }
        __syncthreads();

        bf16x8 af[4], bfx[4];
        #pragma unroll
        for (int i = 0; i < 4; ++i)
            af[i] = frag_from_u32x4(*(const u32x4*)((const char*)lA + aoff + i * 1024));
        #pragma unroll
        for (int j = 0; j < 4; ++j)
            bfx[j] = frag_from_u32x4(*(const u32x4*)((const char*)lX + boff + j * 1024));
        #pragma unroll
        for (int i = 0; i < 4; ++i)
            #pragma unroll
            for (int j = 0; j < 4; ++j)
                acc[i][j] = __builtin_amdgcn_mfma_f32_16x16x32_bf16(af[i], bfx[j], acc[i][j], 0, 0, 0);
        __syncthreads();
    }

    // epilogue: C/D layout col=lane&15, row=(lane>>4)*4+reg
    const int col = lane & 15, row0 = (lane >> 4) * 4;

    if constexpr (QSMT) {
        // fused per-head softmax over 64 output channels (= wave's 64 rows),
        // then TRANSPOSED bf16 write Y[b][l][o] (8B packed stores).
        #pragma unroll
        for (int i = 0; i < 4; ++i)
            #pragma unroll
            for (int r = 0; r < 4; ++r) {
                const float bo = bias[m0 + wm + i * 16 + row0 + r];
                #pragma unroll
                for (int j = 0; j < 4; ++j) acc[i][j][r] += bo;
            }
        float inv[4];
        #pragma unroll
        for (int j = 0; j < 4; ++j) {
            float m = -1e30f;
            #pragma unroll
            for (int i = 0; i < 4; ++i)
                #pragma unroll
                for (int r = 0; r < 4; ++r) m = fmaxf(m, acc[i][j][r]);
            m = fmaxf(m, __shfl_xor(m, 16));
            m = fmaxf(m, __shfl_xor(m, 32));
            float s = 0.f;
            #pragma unroll
            for (int i = 0; i < 4; ++i)
                #pragma unroll
                for (int r = 0; r < 4; ++r) {
                    const float e = __expf(acc[i][j][r] - m);
                    acc[i][j][r] = e;
                    s += e;
                }
            s += __shfl_xor(s, 16);
            s += __shfl_xor(s, 32);
            inv[j] = 1.0f / s;
        }
        unsigned short* Yq = (unsigned short*)Yv;
        #pragma unroll
        for (int j = 0; j < 4; ++j) {
            const size_t rowb = (size_t)b * NL * NC + (size_t)(n0 + wn + j * 16 + col) * NC;
            #pragma unroll
            for (int i = 0; i < 4; ++i) {
                const int o0 = m0 + wm + i * 16 + row0;
                unsigned lo = f2bf(acc[i][j][0] * inv[j]) | ((unsigned)f2bf(acc[i][j][1] * inv[j]) << 16);
                unsigned hi = f2bf(acc[i][j][2] * inv[j]) | ((unsigned)f2bf(acc[i][j][3] * inv[j]) << 16);
                *(unsigned long long*)(Yq + rowb + o0) =
                    (unsigned long long)lo | ((unsigned long long)hi << 32);
            }
        }
    } else {
        #pragma unroll
        for (int i = 0; i < 4; ++i) {
            #pragma unroll
            for (int r = 0; r < 4; ++r) {
                const int o = m0 + wm + i * 16 + row0 + r;
                const float bo = bias[o];
                const size_t rb = (size_t)b * OC * NL + (size_t)o * NL + n0 + wn;
                if constexpr (RESID) {
                    float* Y = (float*)Yv;
                    #pragma unroll
                    for (int j = 0; j < 4; ++j) {
                        const size_t idx = rb + j * 16 + col;
                        Y[idx] = acc[i][j][r] + bo + resid[idx];
                    }
                } else {
                    unsigned short* Y = (unsigned short*)Yv;
                    #pragma unroll
                    for (int j = 0; j < 4; ++j)
                        Y[rb + j * 16 + col] = f2bf(acc[i][j][r] + bo);
                }
            }
        }
    }
}

// in-place softmax over rows of 8192 (bf16), one block per row (K channels of KVp)
__global__ __launch_bounds__(256) void softmax_rows(unsigned short* __restrict__ KV) {
    const int row = blockIdx.x;             // 0..NB*NC-1
    const int t = threadIdx.x;
    const int wave = t >> 6, lane = t & 63;
    unsigned short* p = KV + ((size_t)(row >> 9) * 2 * NC + (row & 511)) * NL;

    float v[32];
    float mx = -1e30f;
    #pragma unroll
    for (int i = 0; i < 4; ++i) {
        u32x4 raw = *(const u32x4*)(p + (size_t)(i * 256 + t) * 8);
        #pragma unroll
        for (int d = 0; d < 4; ++d) {
            unsigned w = raw[d];
            v[i * 8 + d * 2]     = bf2f_lo(w);
            v[i * 8 + d * 2 + 1] = bf2f_hi(w);
        }
        #pragma unroll
        for (int j = 0; j < 8; ++j) mx = fmaxf(mx, v[i * 8 + j]);
    }
    #pragma unroll
    for (int off = 32; off > 0; off >>= 1) mx = fmaxf(mx, __shfl_down(mx, off));
    __shared__ float red[16];
    if (lane == 0) red[wave] = mx;
    __syncthreads();
    mx = fmaxf(fmaxf(red[0], red[1]), fmaxf(red[2], red[3]));

    float s = 0.f;
    #pragma unroll
    for (int i = 0; i < 32; ++i) { v[i] = __expf(v[i] - mx); s += v[i]; }
    #pragma unroll
    for (int off = 32; off > 0; off >>= 1) s += __shfl_down(s, off);
    if (lane == 0) red[8 + wave] = s;
    __syncthreads();
    s = red[8] + red[9] + red[10] + red[11];
    const float inv = 1.0f / s;

    #pragma unroll
    for (int i = 0; i < 4; ++i) {
        u32x4 outw;
        #pragma unroll
        for (int d = 0; d < 4; ++d) {
            unsigned lo = f2bf(v[i * 8 + d * 2] * inv);
            unsigned hi = f2bf(v[i * 8 + d * 2 + 1] * inv);
            outw[d] = lo | (hi << 16);
        }
        *(u32x4*)(p + (size_t)(i * 256 + t) * 8) = outw;
    }
}

// ctx[bh,k,v] = sum_l Ksm[b,h,k,l] * V[b,h,v,l]   grid (64, 16 L-splits), atomicAdd
__global__ __launch_bounds__(256) void ctx_kernel(
    const unsigned short* __restrict__ KV,   // [B][1024][L]: rows 0-511 K(softmaxed), 512-1023 V
    float* __restrict__ ctx)                 // [64][64][64]
{
    const int bh = blockIdx.x;
    const int sp = blockIdx.y;
    const int t = threadIdx.x;
    const int wave = t >> 6, lane = t & 63;
    const int b = bh >> 3, h = bh & 7;
    const size_t base_k = ((size_t)b * 2 * NC + h * ND) * NL;
    const size_t base_v = base_k + (size_t)NC * NL;
    const int i = wave * 16 + (lane & 15);
    const int koff = (lane >> 4) * 8;
    const unsigned short* Ka = KV + base_k + (size_t)i * NL + koff;

    f32x4 acc[4] = {};
    const int l0 = sp * (NL / 16);
    for (int l = l0; l < l0 + (NL / 16); l += 32) {
        bf16x8 a = ld_frag_g16(Ka + l);
        #pragma unroll
        for (int j = 0; j < 4; ++j) {
            bf16x8 bv = ld_frag_g16(KV + base_v + (size_t)(j * 16 + (lane & 15)) * NL + l + koff);
            acc[j] = __builtin_amdgcn_mfma_f32_16x16x32_bf16(a, bv, acc[j], 0, 0, 0);
        }
    }
    const int col = lane & 15, row0 = (lane >> 4) * 4;
    #pragma unroll
    for (int j = 0; j < 4; ++j)
        #pragma unroll
        for (int r = 0; r < 4; ++r)
            atomicAdd(&ctx[(size_t)bh * (ND * ND) + (size_t)(wave * 16 + row0 + r) * ND + j * 16 + col],
                      acc[j][r]);
}

// M_b[o, h*64+k] = sum_v Wr[o, h*64+v] * ctx[b,h,k,v]
// grid 64 blocks (bh), 512 threads = 8 waves; wave covers 64 o-rows
__global__ __launch_bounds__(512) void fold_kernel(
    const unsigned short* __restrict__ Wrb,  // [512][512] bf16
    const float* __restrict__ ctxb,          // [64][64][64]
    unsigned short* __restrict__ Mb)         // [B][512][512] bf16
{
    const int bh = blockIdx.x;
    const int b = bh >> 3, h = bh & 7;
    const int t = threadIdx.x;
    const int wave = t >> 6, lane = t & 63;

    __shared__ unsigned short lc[64 * 66];   // ctx bf16 [k][v], padded stride 66
    const float* cs = ctxb + (size_t)bh * (ND * ND);
    #pragma unroll
    for (int it = 0; it < 8; ++it) {
        int i = it * 512 + t;
        lc[(i >> 6) * 66 + (i & 63)] = f2bf(cs[i]);
    }
    __syncthreads();

    const int koff = (lane >> 4) * 8;
    f32x4 acc[4][4] = {};
    #pragma unroll
    for (int kk = 0; kk < 64; kk += 32) {
        bf16x8 af[4], bfx[4];
        #pragma unroll
        for (int i = 0; i < 4; ++i)
            af[i] = ld_frag_g16(Wrb + (size_t)(wave * 64 + i * 16 + (lane & 15)) * NC
                                + h * ND + kk + koff);
        #pragma unroll
        for (int j = 0; j < 4; ++j)
            bfx[j] = ld_frag_lds(&lc[(j * 16 + (lane & 15)) * 66 + kk + koff]);
        #pragma unroll
        for (int i = 0; i < 4; ++i)
            #pragma unroll
            for (int j = 0; j < 4; ++j)
                acc[i][j] = __builtin_amdgcn_mfma_f32_16x16x32_bf16(af[i], bfx[j], acc[i][j], 0, 0, 0);
    }

    const int col = lane & 15, row0 = (lane >> 4) * 4;
    #pragma unroll
    for (int i = 0; i < 4; ++i)
        #pragma unroll
        for (int r = 0; r < 4; ++r) {
            const int o = wave * 64 + i * 16 + row0 + r;
            #pragma unroll
            for (int j = 0; j < 4; ++j)
                Mb[(size_t)b * NC * NC + (size_t)o * NC + h * ND + j * 16 + col]
                    = f2bf(acc[i][j][r]);
        }
}

extern "C" void kernel_launch(void* const* d_in, const int* in_sizes, int n_in,
                              void* d_out, int out_size, void* d_ws, size_t ws_size,
                              hipStream_t stream) {
    (void)in_sizes; (void)n_in; (void)out_size; (void)ws_size;
    const float* input_   = (const float*)d_in[0];
    const float* context_ = (const float*)d_in[1];
    const float* Wk = (const float*)d_in[2];
    const float* bk = (const float*)d_in[3];
    const float* Wq = (const float*)d_in[4];
    const float* bq = (const float*)d_in[5];
    const float* Wv = (const float*)d_in[6];
    const float* bv = (const float*)d_in[7];
    const float* Wr = (const float*)d_in[8];
    const float* br = (const float*)d_in[9];
    float* out = (float*)d_out;

    // workspace layout (~204 MB, same budget as previous version):
    char* ws = (char*)d_ws;
    unsigned short* Wkvb = (unsigned short*)ws;                     // [1024][512] bf16 = 1 MB
    unsigned short* Wqb  = Wkvb + 2 * NC * NC;                      // 512 KB
    unsigned short* Wrb  = Wqb + NC * NC;                           // 512 KB
    float* bkv  = (float*)(Wrb + NC * NC);                          // 4 KB
    float* ctxb = bkv + 2 * NC;                                     // 1 MB
    unsigned short* KVp = (unsigned short*)(ctxb + NB * NH * ND * ND); // [B][1024][L] = 134 MB
    unsigned short* R2  = KVp + (size_t)NB * 2 * NC * NL;           // 67 MB: Xt_ctx, then Qp
    unsigned short* Mb  = KVp;                                      // reuse KVp after ctx/fold
    unsigned short* Xt_in = (unsigned short*)d_out;                 // scratch in out buffer (67 MB)

    const int wN = NC * NC;
    cvt_w_kernel<<<wN / 256, 256, 0, stream>>>(Wk, Wkvb, wN);
    cvt_w_kernel<<<wN / 256, 256, 0, stream>>>(Wv, Wkvb + wN, wN);
    cvt_w_kernel<<<wN / 256, 256, 0, stream>>>(Wq, Wqb, wN);
    cvt_w_kernel<<<wN / 256, 256, 0, stream>>>(Wr, Wrb, wN);
    concat_bias_kernel<<<4, 256, 0, stream>>>(bk, bv, bkv);
    zero_kernel<<<(NB * NH * ND * ND) / 256, 256, 0, stream>>>(ctxb, NB * NH * ND * ND);

    // pre-transpose X to bf16 [b][l][c] (done ONCE, not MT x per GEMM)
    transpose_cvt_kernel<<<dim3(NL / 64, NC / 64, NB), 256, 0, stream>>>(context_, R2);

    // K+V fused projection: [Wk;Wv] (1024x512) @ context -> KVp
    gemm_kernel<8, false, false, false><<<dim3(64 * 8, NB), 256, 0, stream>>>(
        Wkvb, R2, bkv, nullptr, KVp);

    transpose_cvt_kernel<<<dim3(NL / 64, NC / 64, NB), 256, 0, stream>>>(input_, Xt_in);

    // Q projection + fused per-head softmax, TRANSPOSED output Qp[b][l][c] -> R2
    gemm_kernel<4, false, false, true><<<dim3(64 * 4, NB), 256, 0, stream>>>(
        Wqb, Xt_in, bq, nullptr, R2);

    softmax_rows<<<NB * NC, 256, 0, stream>>>(KVp);
    ctx_kernel<<<dim3(NB * NH, 16), 256, 0, stream>>>(KVp, ctxb);
    fold_kernel<<<NB * NH, 512, 0, stream>>>(Wrb, ctxb, Mb);

    // out = M_b @ Qp^T + br + input   (X = Qp[b][l][c], W = Mb per-batch)
    gemm_kernel<4, true, true, false><<<dim3(64 * 4, NB), 256, 0, stream>>>(
        Mb, R2, br, input_, out);
}